// Round 7
// baseline (935.993 us; speedup 1.0000x reference)
//
#include <hip/hip_runtime.h>
#include <stdint.h>

// WeightOnlyInt8Linear: out[t,o] = sum_k x[t,k] * (int8 w[o,k] * scale[o]) + bias[o]
// M=8192, K=4096, N=11008. x fp32, w int8-as-int32 (harness), out fp32.
// Round 6: read-one-phase-ahead pipeline. Each phase: {ds_read NEXT phase's
// fragments || stage -> counted lgkmcnt (current fragments retired, next's in
// flight) -> MFMA -> counted vmcnt -> barrier}. LDS reads now overlap MFMA.
// Alternating quadrant order per slab parity keeps all fragment groups in
// single register buffers (no extra VGPR). int8 MFMA (v_mfma_i32_16x16x64_i8),
// 256x256 tile, BK=128, 8-slot XOR swizzle (0 conflicts, r4/r5-verified),
// double-buffered 128 KiB LDS, bijective XCD swizzle.

#define TOKENS 8192
#define IN_F   4096
#define OUT_F  11008

#define BM 256
#define BN 256
#define BK 128               // int8 k-slab per LDS tile
#define KT   (IN_F / BK)     // 32
#define MBLK (TOKENS / BM)   // 32
#define NBLK (OUT_F / BN)    // 43
#define NWG  (MBLK * NBLK)   // 1376

static_assert(NWG % 8 == 0, "XCD swizzle requires nwg % 8 == 0");
static_assert(KT % 2 == 0, "double-buffer parity");

#define LDS_BUF   65536      // per buffer: AL|AH|BL|BH regions of 16 KiB
#define LDS_TOTAL 131072

typedef __attribute__((ext_vector_type(4))) float f32x4;
typedef __attribute__((ext_vector_type(4))) int   i32x4;

__device__ __forceinline__ void gload_lds16(const void* g, void* l) {
  typedef const __attribute__((address_space(1))) unsigned int* gp_t;
  typedef __attribute__((address_space(3))) unsigned int* lp_t;
  __builtin_amdgcn_global_load_lds((gp_t)g, (lp_t)l, 16, 0, 0);
}

#define MFMA(d, a, b) \
  asm("v_mfma_i32_16x16x64_i8 %0, %1, %2, %0" : "+v"(d) : "v"(a), "v"(b))

#define BARRIER __builtin_amdgcn_s_barrier()
#define LGKMC_(N)                                              \
  do {                                                         \
    asm volatile("s_waitcnt lgkmcnt(" #N ")" ::: "memory");    \
    __builtin_amdgcn_sched_barrier(0);                         \
  } while (0)
#define LGKMC(N) LGKMC_(N)
#define VMW_(N) asm volatile("s_waitcnt vmcnt(" #N ")" ::: "memory")
#define VMW(N) VMW_(N)

// ---------------- quantize x: per-token absmax -> int8 + sx ----------------
__global__ __launch_bounds__(256) void quant_x_kernel(
    const float* __restrict__ x, signed char* __restrict__ xq,
    float* __restrict__ sx) {
  const int row = blockIdx.x;
  const int tid = threadIdx.x;
  const float* xr = x + (size_t)row * IN_F;
  f32x4 v[4];
#pragma unroll
  for (int p = 0; p < 4; ++p) v[p] = ((const f32x4*)xr)[tid + 256 * p];
  float am = 0.f;
#pragma unroll
  for (int p = 0; p < 4; ++p)
#pragma unroll
    for (int j = 0; j < 4; ++j) am = fmaxf(am, fabsf(v[p][j]));
#pragma unroll
  for (int off = 32; off; off >>= 1) am = fmaxf(am, __shfl_xor(am, off, 64));
  __shared__ float wmax[4];
  if ((tid & 63) == 0) wmax[tid >> 6] = am;
  __syncthreads();
  am = fmaxf(fmaxf(wmax[0], wmax[1]), fmaxf(wmax[2], wmax[3]));
  const float inv = (am > 0.f) ? 127.0f / am : 0.f;
  if (tid == 0) sx[row] = (am > 0.f) ? am / 127.0f : 1.0f;
  int* xqi = (int*)(xq + (size_t)row * IN_F);
#pragma unroll
  for (int p = 0; p < 4; ++p) {
    int pk = 0;
#pragma unroll
    for (int j = 0; j < 4; ++j) {
      int q = (int)rintf(v[p][j] * inv);   // |x|<=am -> q in [-127,127]
      pk |= (q & 0xff) << (8 * j);
    }
    xqi[tid + 256 * p] = pk;
  }
}

// ---------------- convert w: int32 (values in [-127,127]) -> int8 ----------
__global__ void cvt_w_kernel(const int* __restrict__ w,
                             signed char* __restrict__ wq, int n16) {
  int i = blockIdx.x * blockDim.x + threadIdx.x;
  int stride = gridDim.x * blockDim.x;
  for (int c = i; c < n16; c += stride) {
    const i32x4* src = (const i32x4*)w + (size_t)c * 4;
    i32x4 outv;
#pragma unroll
    for (int q = 0; q < 4; ++q) {
      i32x4 v = src[q];
      outv[q] = (v[0] & 0xff) | ((v[1] & 0xff) << 8) |
                ((v[2] & 0xff) << 16) | (v[3] << 24);
    }
    ((i32x4*)wq)[c] = outv;
  }
}

// ---------------- int8 MFMA GEMM, 256x256, read-ahead pipelined -------------
// Regions per buffer (16 KiB = 128 rows x 128 B, row = one K-slab of 128 i8):
//   AL: A rows {0-63,128-191}; AH: {64-127,192-255};
//   BL: B rows {wn*64+0..31};  BH: {wn*64+32..63}.
// Row r slot j holds global chunk j^(r&7) (both-sides involution, 0 conflicts).
// Quadrants: Q00=(mLo,nLo:arLo,brLo) Q01=(mLo,nHi:arLo,brHi)
//            Q11=(mHi,nHi:arHi,brHi) Q10=(mHi,nLo:arHi,brLo)
// Even slab: Q00,Q01,Q11,Q10 ; Odd slab: Q01,Q00,Q10,Q11 — the group read in
// each last phase lands in buffers dead since 2 phases (no double-buffering).
__global__ __launch_bounds__(512, 2) void gemm_i8_kernel(
    const signed char* __restrict__ A,   // [TOKENS][IN_F] int8
    const signed char* __restrict__ Bm,  // [OUT_F][IN_F] int8
    const float* __restrict__ sx,        // [TOKENS] per-token x scale
    const float* __restrict__ scale,     // [OUT_F]
    const float* __restrict__ bias,      // [OUT_F]
    float* __restrict__ C)               // [TOKENS][OUT_F] fp32
{
  extern __shared__ char lds[];          // 128 KiB

  const int tid  = threadIdx.x;
  const int lane = tid & 63;
  const int wave = tid >> 6;   // 0..7
  const int wm   = wave >> 2;  // 0..1
  const int wn   = wave & 3;   // 0..3
  const int grp  = lane >> 4;  // 0..3
  const int rsel = lane & 15;  // 0..15

  int bid = blockIdx.x;
  int wg  = (bid & 7) * (NWG / 8) + (bid >> 3);
  const int m_idx = wg % MBLK;
  const int n_idx = wg / MBLK;
  const int row0 = m_idx * BM;
  const int col0 = n_idx * BN;

  // staging: per region 1024 chunks of 16 B; thread covers c = p*512+tid.
  const int r0  = tid >> 3;                      // region row (p=0); p=1: +64
  const int jg  = (tid & 7) ^ (r0 & 7);          // pre-swizzled slot
  const int gAL0 = r0;
  const int gAL1 = 128 + r0;
  const int gBL0 = r0 + (r0 & 32);
  const int gBL1 = 128 + r0 + (r0 & 32);
  const signed char* pAL0 = A  + (size_t)(row0 + gAL0) * IN_F + jg * 16;
  const signed char* pAL1 = A  + (size_t)(row0 + gAL1) * IN_F + jg * 16;
  const signed char* pAH0 = pAL0 + (size_t)64 * IN_F;
  const signed char* pAH1 = pAL1 + (size_t)64 * IN_F;
  const signed char* pBL0 = Bm + (size_t)(col0 + gBL0) * IN_F + jg * 16;
  const signed char* pBL1 = Bm + (size_t)(col0 + gBL1) * IN_F + jg * 16;
  const signed char* pBH0 = pBL0 + (size_t)32 * IN_F;
  const signed char* pBH1 = pBL1 + (size_t)32 * IN_F;
  const int stBase = wave * 1024;

  auto stAL = [&](int bo, int t2) {
    const int ko = t2 * BK;
    gload_lds16(pAL0 + ko, lds + bo + 0     + stBase);
    gload_lds16(pAL1 + ko, lds + bo + 8192  + stBase);
  };
  auto stAH = [&](int bo, int t2) {
    const int ko = t2 * BK;
    gload_lds16(pAH0 + ko, lds + bo + 16384 + stBase);
    gload_lds16(pAH1 + ko, lds + bo + 24576 + stBase);
  };
  auto stBL = [&](int bo, int t2) {
    const int ko = t2 * BK;
    gload_lds16(pBL0 + ko, lds + bo + 32768 + stBase);
    gload_lds16(pBL1 + ko, lds + bo + 40960 + stBase);
  };
  auto stBH = [&](int bo, int t2) {
    const int ko = t2 * BK;
    gload_lds16(pBH0 + ko, lds + bo + 49152 + stBase);
    gload_lds16(pBH1 + ko, lds + bo + 57344 + stBase);
  };

  const int swz0  = (grp ^ (rsel & 7)) << 4;
  const int swz1  = swz0 ^ 64;
  const int aBase = wm * 8192 + rsel * 128;
  const int bBase = wn * 4096 + rsel * 128;

  i32x4 zero = {0, 0, 0, 0};
  i32x4 acc[8][4];
#pragma unroll
  for (int m = 0; m < 8; ++m)
#pragma unroll
    for (int n = 0; n < 4; ++n) acc[m][n] = zero;

  i32x4 arLo[8], arHi[8], brLo[4], brHi[4];

#define DS_AL(BO, MI, SW) (*(const i32x4*)(lds + (BO) + 0     + aBase + (MI)*2048 + (SW)))
#define DS_AH(BO, MI, SW) (*(const i32x4*)(lds + (BO) + 16384 + aBase + (MI)*2048 + (SW)))
#define DS_BL(BO, NI, SW) (*(const i32x4*)(lds + (BO) + 32768 + bBase + (NI)*2048 + (SW)))
#define DS_BH(BO, NI, SW) (*(const i32x4*)(lds + (BO) + 49152 + bBase + (NI)*2048 + (SW)))

#define RD_ARLO(BO)                                                            \
  _Pragma("unroll") for (int m = 0; m < 4; ++m) {                              \
    arLo[m * 2]     = DS_AL(BO, m, swz0);                                      \
    arLo[m * 2 + 1] = DS_AL(BO, m, swz1);                                      \
  }
#define RD_ARHI(BO)                                                            \
  _Pragma("unroll") for (int m = 0; m < 4; ++m) {                              \
    arHi[m * 2]     = DS_AH(BO, m, swz0);                                      \
    arHi[m * 2 + 1] = DS_AH(BO, m, swz1);                                      \
  }
#define RD_BRLO(BO)                                                            \
  _Pragma("unroll") for (int n = 0; n < 2; ++n) {                              \
    brLo[n * 2]     = DS_BL(BO, n, swz0);                                      \
    brLo[n * 2 + 1] = DS_BL(BO, n, swz1);                                      \
  }
#define RD_BRHI(BO)                                                            \
  _Pragma("unroll") for (int n = 0; n < 2; ++n) {                              \
    brHi[n * 2]     = DS_BH(BO, n, swz0);                                      \
    brHi[n * 2 + 1] = DS_BH(BO, n, swz1);                                      \
  }

#define MM_Q00                                                                 \
  _Pragma("unroll") for (int m = 0; m < 4; ++m)                                \
    _Pragma("unroll") for (int n = 0; n < 2; ++n)                              \
      _Pragma("unroll") for (int kk = 0; kk < 2; ++kk)                         \
        MFMA(acc[m][n], arLo[m * 2 + kk], brLo[n * 2 + kk]);
#define MM_Q01                                                                 \
  _Pragma("unroll") for (int m = 0; m < 4; ++m)                                \
    _Pragma("unroll") for (int n = 0; n < 2; ++n)                              \
      _Pragma("unroll") for (int kk = 0; kk < 2; ++kk)                         \
        MFMA(acc[m][n + 2], arLo[m * 2 + kk], brHi[n * 2 + kk]);
#define MM_Q11                                                                 \
  _Pragma("unroll") for (int m = 0; m < 4; ++m)                                \
    _Pragma("unroll") for (int n = 0; n < 2; ++n)                              \
      _Pragma("unroll") for (int kk = 0; kk < 2; ++kk)                         \
        MFMA(acc[m + 4][n + 2], arHi[m * 2 + kk], brHi[n * 2 + kk]);
#define MM_Q10                                                                 \
  _Pragma("unroll") for (int m = 0; m < 4; ++m)                                \
    _Pragma("unroll") for (int n = 0; n < 2; ++n)                              \
      _Pragma("unroll") for (int kk = 0; kk < 2; ++kk)                         \
        MFMA(acc[m + 4][n], arHi[m * 2 + kk], brLo[n * 2 + kk]);

#define PRIO1 __builtin_amdgcn_s_setprio(1)
#define PRIO0 __builtin_amdgcn_s_setprio(0)

  // EVEN slab (buffer BO): phases P0..P3 = Q00,Q01,Q11,Q10.
  //   P0: rd brHi=BH(BO,T)                      ; lgkm(4) ; Q00 ; VMW(W0)
  //   P1: rd arHi=AH(BO,T); st AL,BL(T+2)->BO   ; lgkm(8) ; Q01
  //   P2:                  st BH(T+2)->BO       ; lgkm(0) ; Q11 ; VMW(W2)
  //   P3: rd arLo,brHi = AL,BH(BO^,T+1); st AH(T+2)->BO ; lgkm(12); Q10; VMW(W3)
#define TILE_EVEN(BO, T, STG, W0, W2, W3)                                      \
  {                                                                            \
    RD_BRHI(BO);                                                               \
    LGKMC(4);                                                                  \
    PRIO1; MM_Q00; PRIO0;                                                      \
    VMW(W0); BARRIER;                                                          \
    RD_ARHI(BO);                                                               \
    if (STG) { stAL((BO), (T) + 2); stBL((BO), (T) + 2); }                     \
    LGKMC(8);                                                                  \
    PRIO1; MM_Q01; PRIO0;                                                      \
    BARRIER;                                                                   \
    if (STG) stBH((BO), (T) + 2);                                              \
    LGKMC(0);                                                                  \
    PRIO1; MM_Q11; PRIO0;                                                      \
    VMW(W2); BARRIER;                                                          \
    RD_ARLO((BO) ^ LDS_BUF);                                                   \
    RD_BRHI((BO) ^ LDS_BUF);                                                   \
    if (STG) stAH((BO), (T) + 2);                                              \
    LGKMC(12);                                                                 \
    PRIO1; MM_Q10; PRIO0;                                                      \
    VMW(W3); BARRIER;                                                          \
  }

  // ODD slab (buffer BO): phases P0..P3 = Q01,Q00,Q10,Q11.
  //   P0: rd brLo=BL(BO,T)                      ; lgkm(4) ; Q01 ; VMW(W0)
  //   P1: rd arHi=AH(BO,T); st AL,BH(T+2)->BO   ; lgkm(8) ; Q00
  //   P2:                  st BL(T+2)->BO       ; lgkm(0) ; Q10 ; VMW(W2)
  //   P3: rd arLo,brLo = AL,BL(BO^,T+1) if RDN; st AH(T+2)->BO; lgkm(LG3); Q11; VMW(W3)
#define TILE_ODD(BO, T, STG, RDN, W0, W2, W3, LG3)                             \
  {                                                                            \
    RD_BRLO(BO);                                                               \
    LGKMC(4);                                                                  \
    PRIO1; MM_Q01; PRIO0;                                                      \
    VMW(W0); BARRIER;                                                          \
    RD_ARHI(BO);                                                               \
    if (STG) { stAL((BO), (T) + 2); stBH((BO), (T) + 2); }                     \
    LGKMC(8);                                                                  \
    PRIO1; MM_Q00; PRIO0;                                                      \
    BARRIER;                                                                   \
    if (STG) stBL((BO), (T) + 2);                                              \
    LGKMC(0);                                                                  \
    PRIO1; MM_Q10; PRIO0;                                                      \
    VMW(W2); BARRIER;                                                          \
    if (RDN) { RD_ARLO((BO) ^ LDS_BUF); RD_BRLO((BO) ^ LDS_BUF); }             \
    if (STG) stAH((BO), (T) + 2);                                              \
    LGKMC(LG3);                                                                \
    PRIO1; MM_Q11; PRIO0;                                                      \
    VMW(W3); BARRIER;                                                          \
  }

  // Prologue: stage slabs 0 and 1 in steady-state-consistent order:
  //   [AL0,BL0][BH0][AH0] | [AL1,BH1][BL1][AH1]   (16 loads)
  stAL(0, 0); stBL(0, 0);
  stBH(0, 0);
  stAH(0, 0);
  stAL(LDS_BUF, 1); stBH(LDS_BUF, 1);
  stBL(LDS_BUF, 1);
  stAH(LDS_BUF, 1);
  VMW(12);          // AL0,BL0 (oldest 4) landed
  BARRIER;
  RD_ARLO(0);       // pre-read slab 0's P0 group
  RD_BRLO(0);
  VMW(10);          // BH0 landed (10 newer in flight)
  BARRIER;

  for (int t2 = 0; t2 < KT - 2; t2 += 2) {
    TILE_EVEN(0, t2, 1, 8, 10, 10);
    TILE_ODD(LDS_BUF, t2 + 1, 1, 1, 8, 10, 10, 12);
  }
  TILE_EVEN(0, KT - 2, 0, 8, 4, 2);
  TILE_ODD(LDS_BUF, KT - 1, 0, 0, 0, 0, 0, 0);

#undef TILE_EVEN
#undef TILE_ODD

  asm volatile("s_nop 7\n\ts_nop 7" :::);

  // Epilogue: C/D layout col=lane&15, row=(lane>>4)*4+v (dtype-independent).
#pragma unroll
  for (int n = 0; n < 4; ++n) {
    int o = col0 + wn * 64 + n * 16 + rsel;
    float s  = scale[o];
    float bz = bias[o];
#pragma unroll
    for (int m = 0; m < 8; ++m) {
      int tr = row0 + wm * 128 + m * 16 + grp * 4;
      const f32x4 sxv = *(const f32x4*)(sx + tr);
      float* cp = C + (size_t)tr * OUT_F + o;
      i32x4 v = acc[m][n];
      cp[0 * (size_t)OUT_F] = (float)v[0] * (sxv[0] * s) + bz;
      cp[1 * (size_t)OUT_F] = (float)v[1] * (sxv[1] * s) + bz;
      cp[2 * (size_t)OUT_F] = (float)v[2] * (sxv[2] * s) + bz;
      cp[3 * (size_t)OUT_F] = (float)v[3] * (sxv[3] * s) + bz;
    }
  }
}

// ---------------- fallback (only if ws too small): naive fp32 ----------------
__global__ void gemm_naive_kernel(const float* __restrict__ x,
                                  const int* __restrict__ w,
                                  const float* __restrict__ sc,
                                  const float* __restrict__ bs,
                                  float* __restrict__ out) {
  long long idx = (long long)blockIdx.x * blockDim.x + threadIdx.x;
  long long total = (long long)TOKENS * OUT_F;
  if (idx >= total) return;
  int t = (int)(idx / OUT_F);
  int o = (int)(idx % OUT_F);
  const float* xp = x + (size_t)t * IN_F;
  const int* wp = w + (size_t)o * IN_F;
  float acc = 0.f;
  for (int k = 0; k < IN_F; k += 4) {
    i32x4 wv = *(const i32x4*)(wp + k);
    f32x4 xv = *(const f32x4*)(xp + k);
    acc += xv[0] * (float)wv[0] + xv[1] * (float)wv[1]
         + xv[2] * (float)wv[2] + xv[3] * (float)wv[3];
  }
  out[idx] = acc * sc[o] + bs[o];
}

extern "C" void kernel_launch(void* const* d_in, const int* in_sizes, int n_in,
                              void* d_out, int out_size, void* d_ws, size_t ws_size,
                              hipStream_t stream) {
  const float* x  = (const float*)d_in[0];
  const int*   qw = (const int*)d_in[1];     // int8 values materialized as int32
  const float* sc = (const float*)d_in[2];
  const float* bs = (const float*)d_in[3];
  float* out = (float*)d_out;

  const size_t xqBytes = (size_t)TOKENS * IN_F;       // 32 MiB
  const size_t wqBytes = (size_t)OUT_F * IN_F;        // 43 MiB
  const size_t sxBytes = (size_t)TOKENS * sizeof(float);

  if (ws_size >= xqBytes + wqBytes + sxBytes) {
    signed char* xq = (signed char*)d_ws;
    signed char* wq = (signed char*)((char*)d_ws + xqBytes);
    float*       sx = (float*)((char*)d_ws + xqBytes + wqBytes);
    quant_x_kernel<<<TOKENS, 256, 0, stream>>>(x, xq, sx);
    cvt_w_kernel<<<2048, 256, 0, stream>>>(qw, wq, OUT_F * IN_F / 16);
    (void)hipFuncSetAttribute((const void*)gemm_i8_kernel,
                              hipFuncAttributeMaxDynamicSharedMemorySize,
                              LDS_TOTAL);
    gemm_i8_kernel<<<NWG, 512, LDS_TOTAL, stream>>>(xq, wq, sx, sc, bs, out);
  } else {
    long long total = (long long)TOKENS * OUT_F;
    int blocks = (int)((total + 255) / 256);
    gemm_naive_kernel<<<blocks, 256, 0, stream>>>(x, qw, sc, bs, out);
  }
}

// Round 9
// 516.151 us; speedup vs baseline: 1.8134x; 1.8134x over previous
//
#include <hip/hip_runtime.h>
#include <stdint.h>

// WeightOnlyInt8Linear: out[t,o] = sum_k x[t,k] * (int8 w[o,k] * scale[o]) + bias[o]
// M=8192, K=4096, N=11008. x fp32, w int8-as-int32 (harness), out fp32.
// Round 8: revert to the PROVEN round-5 kernel (449us GEMM, absmax 4.5,
// 0 bank conflicts) with exactly one change: single barrier per phase
// (8 -> 4 barriers/slab). Phase = [reads; stage; lgkmcnt(0)+sched_barrier;
// MFMA (setprio); counted vmcnt; s_barrier]. WAR safety: every region's
// re-stage is >=1 barrier after the segment that last read it, and those
// reads retire at that segment's LGKM0 (before its trailing barrier).
// vmcnt plan is wave-local and unchanged from r5.
// int8 MFMA 16x16x64 (exact int32 accum), per-token x quant (absmax/127),
// 256x256 tile, BK=128, 8-slot XOR swizzle, double-buffered 128 KiB LDS,
// bijective XCD swizzle.

#define TOKENS 8192
#define IN_F   4096
#define OUT_F  11008

#define BM 256
#define BN 256
#define BK 128               // int8 k-slab per LDS tile
#define KT   (IN_F / BK)     // 32
#define MBLK (TOKENS / BM)   // 32
#define NBLK (OUT_F / BN)    // 43
#define NWG  (MBLK * NBLK)   // 1376

static_assert(NWG % 8 == 0, "XCD swizzle requires nwg % 8 == 0");
static_assert(KT % 2 == 0, "double-buffer parity");

#define LDS_BUF   65536      // per buffer: AL|AH|BL|BH regions of 16 KiB
#define LDS_TOTAL 131072

typedef __attribute__((ext_vector_type(4))) float f32x4;
typedef __attribute__((ext_vector_type(4))) int   i32x4;

__device__ __forceinline__ void gload_lds16(const void* g, void* l) {
  typedef const __attribute__((address_space(1))) unsigned int* gp_t;
  typedef __attribute__((address_space(3))) unsigned int* lp_t;
  __builtin_amdgcn_global_load_lds((gp_t)g, (lp_t)l, 16, 0, 0);
}

#define MFMA(d, a, b) \
  asm("v_mfma_i32_16x16x64_i8 %0, %1, %2, %0" : "+v"(d) : "v"(a), "v"(b))

#define BARRIER __builtin_amdgcn_s_barrier()
#define LGKM0                                                  \
  do {                                                         \
    asm volatile("s_waitcnt lgkmcnt(0)" ::: "memory");         \
    __builtin_amdgcn_sched_barrier(0);                         \
  } while (0)
#define VMW_(N) asm volatile("s_waitcnt vmcnt(" #N ")" ::: "memory")
#define VMW(N) VMW_(N)

// ---------------- quantize x: per-token absmax -> int8 + sx ----------------
__global__ __launch_bounds__(256) void quant_x_kernel(
    const float* __restrict__ x, signed char* __restrict__ xq,
    float* __restrict__ sx) {
  const int row = blockIdx.x;
  const int tid = threadIdx.x;
  const float* xr = x + (size_t)row * IN_F;
  f32x4 v[4];
#pragma unroll
  for (int p = 0; p < 4; ++p) v[p] = ((const f32x4*)xr)[tid + 256 * p];
  float am = 0.f;
#pragma unroll
  for (int p = 0; p < 4; ++p)
#pragma unroll
    for (int j = 0; j < 4; ++j) am = fmaxf(am, fabsf(v[p][j]));
#pragma unroll
  for (int off = 32; off; off >>= 1) am = fmaxf(am, __shfl_xor(am, off, 64));
  __shared__ float wmax[4];
  if ((tid & 63) == 0) wmax[tid >> 6] = am;
  __syncthreads();
  am = fmaxf(fmaxf(wmax[0], wmax[1]), fmaxf(wmax[2], wmax[3]));
  const float inv = (am > 0.f) ? 127.0f / am : 0.f;
  if (tid == 0) sx[row] = (am > 0.f) ? am / 127.0f : 1.0f;
  int* xqi = (int*)(xq + (size_t)row * IN_F);
#pragma unroll
  for (int p = 0; p < 4; ++p) {
    int pk = 0;
#pragma unroll
    for (int j = 0; j < 4; ++j) {
      int q = (int)rintf(v[p][j] * inv);   // |x|<=am -> q in [-127,127]
      pk |= (q & 0xff) << (8 * j);
    }
    xqi[tid + 256 * p] = pk;
  }
}

// ---------------- convert w: int32 (values in [-127,127]) -> int8 ----------
__global__ void cvt_w_kernel(const int* __restrict__ w,
                             signed char* __restrict__ wq, int n16) {
  int i = blockIdx.x * blockDim.x + threadIdx.x;
  int stride = gridDim.x * blockDim.x;
  for (int c = i; c < n16; c += stride) {
    const i32x4* src = (const i32x4*)w + (size_t)c * 4;
    i32x4 outv;
#pragma unroll
    for (int q = 0; q < 4; ++q) {
      i32x4 v = src[q];
      outv[q] = (v[0] & 0xff) | ((v[1] & 0xff) << 8) |
                ((v[2] & 0xff) << 16) | (v[3] << 24);
    }
    ((i32x4*)wq)[c] = outv;
  }
}

// ---------------- int8 MFMA GEMM, 256x256, 4-phase pipelined ----------------
// Regions per buffer (16 KiB = 128 rows x 128 B, row = one K-slab of 128 i8):
//   AL: A rows {0-63,128-191}; AH: {64-127,192-255};
//   BL: B rows {wn*64+0..31};  BH: {wn*64+32..63}.
// Row r slot j holds global chunk j^(r&7) (both-sides involution; 0 conflicts
// measured r4/r5). Fragment chunk jw -> byte (jw^(rsel&7))<<4 = swz0 ^ kk*64.
__global__ __launch_bounds__(512) void gemm_i8_kernel(
    const signed char* __restrict__ A,   // [TOKENS][IN_F] int8
    const signed char* __restrict__ Bm,  // [OUT_F][IN_F] int8
    const float* __restrict__ sx,        // [TOKENS] per-token x scale
    const float* __restrict__ scale,     // [OUT_F]
    const float* __restrict__ bias,      // [OUT_F]
    float* __restrict__ C)               // [TOKENS][OUT_F] fp32
{
  extern __shared__ char lds[];          // 128 KiB

  const int tid  = threadIdx.x;
  const int lane = tid & 63;
  const int wave = tid >> 6;   // 0..7
  const int wm   = wave >> 2;  // 0..1
  const int wn   = wave & 3;   // 0..3
  const int grp  = lane >> 4;  // 0..3
  const int rsel = lane & 15;  // 0..15

  int bid = blockIdx.x;
  int wg  = (bid & 7) * (NWG / 8) + (bid >> 3);
  const int m_idx = wg % MBLK;
  const int n_idx = wg / MBLK;
  const int row0 = m_idx * BM;
  const int col0 = n_idx * BN;

  // staging: per region 1024 chunks of 16 B; thread covers c = p*512+tid.
  const int r0  = tid >> 3;                      // region row (p=0); p=1: +64
  const int jg  = (tid & 7) ^ (r0 & 7);          // pre-swizzled slot
  const int gAL0 = r0;
  const int gAL1 = 128 + r0;
  const int gBL0 = r0 + (r0 & 32);
  const int gBL1 = 128 + r0 + (r0 & 32);
  const signed char* pAL0 = A  + (size_t)(row0 + gAL0) * IN_F + jg * 16;
  const signed char* pAL1 = A  + (size_t)(row0 + gAL1) * IN_F + jg * 16;
  const signed char* pAH0 = pAL0 + (size_t)64 * IN_F;
  const signed char* pAH1 = pAL1 + (size_t)64 * IN_F;
  const signed char* pBL0 = Bm + (size_t)(col0 + gBL0) * IN_F + jg * 16;
  const signed char* pBL1 = Bm + (size_t)(col0 + gBL1) * IN_F + jg * 16;
  const signed char* pBH0 = pBL0 + (size_t)32 * IN_F;
  const signed char* pBH1 = pBL1 + (size_t)32 * IN_F;
  const int stBase = wave * 1024;

  auto stALBL = [&](int bo, int t2) {            // 4 gloads
    const int ko = t2 * BK;
    gload_lds16(pAL0 + ko, lds + bo + 0     + stBase);
    gload_lds16(pAL1 + ko, lds + bo + 8192  + stBase);
    gload_lds16(pBL0 + ko, lds + bo + 32768 + stBase);
    gload_lds16(pBL1 + ko, lds + bo + 40960 + stBase);
  };
  auto stBH = [&](int bo, int t2) {              // 2 gloads
    const int ko = t2 * BK;
    gload_lds16(pBH0 + ko, lds + bo + 49152 + stBase);
    gload_lds16(pBH1 + ko, lds + bo + 57344 + stBase);
  };
  auto stAH = [&](int bo, int t2) {              // 2 gloads
    const int ko = t2 * BK;
    gload_lds16(pAH0 + ko, lds + bo + 16384 + stBase);
    gload_lds16(pAH1 + ko, lds + bo + 24576 + stBase);
  };

  const int swz0  = (grp ^ (rsel & 7)) << 4;
  const int swz1  = swz0 ^ 64;
  const int aBase = wm * 8192 + rsel * 128;
  const int bBase = wn * 4096 + rsel * 128;

  i32x4 zero = {0, 0, 0, 0};
  i32x4 acc[8][4];
#pragma unroll
  for (int m = 0; m < 8; ++m)
#pragma unroll
    for (int n = 0; n < 4; ++n) acc[m][n] = zero;

#define DS_AL(BO, MI, SW) (*(const i32x4*)(lds + (BO) + 0     + aBase + (MI)*2048 + (SW)))
#define DS_AH(BO, MI, SW) (*(const i32x4*)(lds + (BO) + 16384 + aBase + (MI)*2048 + (SW)))
#define DS_BL(BO, NI, SW) (*(const i32x4*)(lds + (BO) + 32768 + bBase + (NI)*2048 + (SW)))
#define DS_BH(BO, NI, SW) (*(const i32x4*)(lds + (BO) + 49152 + bBase + (NI)*2048 + (SW)))

  // Schedule identical to r5 except ONE barrier per phase.
  // Phase = [reads; stage; LGKM0; MFMA(setprio); VMW; BARRIER].
  // vmcnt plan (unchanged from r5, wave-local, in-order retirement):
  //   ph1 stages ALBL(t+2)[4], ph2 stages BH(t+2)[2], ph3 stages AH(t+2)[2]
  //   waits: ph0 end VMW(10) -> BH(t) landed; ph1 end VMW(12) -> AH(t);
  //          ph3 end VMW(12) -> ALBL(t+1).
#define TILE(BO, T, DO_STAGE, W0, W1, W3)                                      \
  {                                                                            \
    i32x4 arLo[8], arHi[8], brLo[4], brHi[4];                                  \
    /* ---- ph0: read A-lo + B-lo ; MM Q00 ---- */                             \
    _Pragma("unroll") for (int m = 0; m < 4; ++m) {                            \
      arLo[m * 2]     = DS_AL(BO, m, swz0);                                    \
      arLo[m * 2 + 1] = DS_AL(BO, m, swz1);                                    \
    }                                                                          \
    _Pragma("unroll") for (int n = 0; n < 2; ++n) {                            \
      brLo[n * 2]     = DS_BL(BO, n, swz0);                                    \
      brLo[n * 2 + 1] = DS_BL(BO, n, swz1);                                    \
    }                                                                          \
    LGKM0;                                                                     \
    __builtin_amdgcn_s_setprio(1);                                             \
    _Pragma("unroll") for (int m = 0; m < 4; ++m)                              \
      _Pragma("unroll") for (int n = 0; n < 2; ++n)                            \
        _Pragma("unroll") for (int kk = 0; kk < 2; ++kk)                       \
          MFMA(acc[m][n], arLo[m * 2 + kk], brLo[n * 2 + kk]);                 \
    __builtin_amdgcn_s_setprio(0);                                             \
    VMW(W0);                                                                   \
    BARRIER;                                                                   \
    /* ---- ph1: read B-hi; stage AL,BL(T+2); MM Q01 ---- */                   \
    _Pragma("unroll") for (int n = 0; n < 2; ++n) {                            \
      brHi[n * 2]     = DS_BH(BO, n, swz0);                                    \
      brHi[n * 2 + 1] = DS_BH(BO, n, swz1);                                    \
    }                                                                          \
    if (DO_STAGE) stALBL((BO), (T) + 2);                                       \
    LGKM0;                                                                     \
    __builtin_amdgcn_s_setprio(1);                                             \
    _Pragma("unroll") for (int m = 0; m < 4; ++m)                              \
      _Pragma("unroll") for (int n = 0; n < 2; ++n)                            \
        _Pragma("unroll") for (int kk = 0; kk < 2; ++kk)                       \
          MFMA(acc[m][n + 2], arLo[m * 2 + kk], brHi[n * 2 + kk]);             \
    __builtin_amdgcn_s_setprio(0);                                             \
    VMW(W1);                                                                   \
    BARRIER;                                                                   \
    /* ---- ph2: read A-hi; stage BH(T+2); MM Q11 ---- */                      \
    _Pragma("unroll") for (int m = 0; m < 4; ++m) {                            \
      arHi[m * 2]     = DS_AH(BO, m, swz0);                                    \
      arHi[m * 2 + 1] = DS_AH(BO, m, swz1);                                    \
    }                                                                          \
    if (DO_STAGE) stBH((BO), (T) + 2);                                         \
    LGKM0;                                                                     \
    __builtin_amdgcn_s_setprio(1);                                             \
    _Pragma("unroll") for (int m = 0; m < 4; ++m)                              \
      _Pragma("unroll") for (int n = 0; n < 2; ++n)                            \
        _Pragma("unroll") for (int kk = 0; kk < 2; ++kk)                       \
          MFMA(acc[m + 4][n + 2], arHi[m * 2 + kk], brHi[n * 2 + kk]);         \
    __builtin_amdgcn_s_setprio(0);                                             \
    BARRIER;                                                                   \
    /* ---- ph3: stage AH(T+2); MM Q10 from held regs ---- */                  \
    if (DO_STAGE) stAH((BO), (T) + 2);                                         \
    __builtin_amdgcn_s_setprio(1);                                             \
    _Pragma("unroll") for (int m = 0; m < 4; ++m)                              \
      _Pragma("unroll") for (int n = 0; n < 2; ++n)                            \
        _Pragma("unroll") for (int kk = 0; kk < 2; ++kk)                       \
          MFMA(acc[m + 4][n], arHi[m * 2 + kk], brLo[n * 2 + kk]);             \
    __builtin_amdgcn_s_setprio(0);                                             \
    VMW(W3);                                                                   \
    BARRIER;                                                                   \
  }

  // Prologue: stage slabs 0 and 1 in steady-state issue order (16 loads).
  stALBL(0, 0);
  stBH(0, 0);
  stAH(0, 0);
  stALBL(LDS_BUF, 1);
  stBH(LDS_BUF, 1);
  stAH(LDS_BUF, 1);
  VMW(12);   // oldest 4 (ALBL of slab 0) landed; 12 newer stay in flight
  BARRIER;

  for (int t2 = 0; t2 < KT - 2; t2 += 2) {
    TILE(0,       t2,     true, 10, 12, 12);
    TILE(LDS_BUF, t2 + 1, true, 10, 12, 12);
  }
  TILE(0,       KT - 2, false, 10, 8, 4);
  TILE(LDS_BUF, KT - 1, false, 2, 0, 0);

#undef TILE
#undef DS_AL
#undef DS_AH
#undef DS_BL
#undef DS_BH

  asm volatile("s_nop 7\n\ts_nop 7" :::);

  // Epilogue: C/D layout col=lane&15, row=(lane>>4)*4+v (dtype-independent).
#pragma unroll
  for (int n = 0; n < 4; ++n) {
    int o = col0 + wn * 64 + n * 16 + rsel;
    float s  = scale[o];
    float bz = bias[o];
#pragma unroll
    for (int m = 0; m < 8; ++m) {
      int tr = row0 + wm * 128 + m * 16 + grp * 4;
      const f32x4 sxv = *(const f32x4*)(sx + tr);
      float* cp = C + (size_t)tr * OUT_F + o;
      i32x4 v = acc[m][n];
      cp[0 * (size_t)OUT_F] = (float)v[0] * (sxv[0] * s) + bz;
      cp[1 * (size_t)OUT_F] = (float)v[1] * (sxv[1] * s) + bz;
      cp[2 * (size_t)OUT_F] = (float)v[2] * (sxv[2] * s) + bz;
      cp[3 * (size_t)OUT_F] = (float)v[3] * (sxv[3] * s) + bz;
    }
  }
}

// ---------------- fallback (only if ws too small): naive fp32 ----------------
__global__ void gemm_naive_kernel(const float* __restrict__ x,
                                  const int* __restrict__ w,
                                  const float* __restrict__ sc,
                                  const float* __restrict__ bs,
                                  float* __restrict__ out) {
  long long idx = (long long)blockIdx.x * blockDim.x + threadIdx.x;
  long long total = (long long)TOKENS * OUT_F;
  if (idx >= total) return;
  int t = (int)(idx / OUT_F);
  int o = (int)(idx % OUT_F);
  const float* xp = x + (size_t)t * IN_F;
  const int* wp = w + (size_t)o * IN_F;
  float acc = 0.f;
  for (int k = 0; k < IN_F; k += 4) {
    i32x4 wv = *(const i32x4*)(wp + k);
    f32x4 xv = *(const f32x4*)(xp + k);
    acc += xv[0] * (float)wv[0] + xv[1] * (float)wv[1]
         + xv[2] * (float)wv[2] + xv[3] * (float)wv[3];
  }
  out[idx] = acc * sc[o] + bs[o];
}

extern "C" void kernel_launch(void* const* d_in, const int* in_sizes, int n_in,
                              void* d_out, int out_size, void* d_ws, size_t ws_size,
                              hipStream_t stream) {
  const float* x  = (const float*)d_in[0];
  const int*   qw = (const int*)d_in[1];     // int8 values materialized as int32
  const float* sc = (const float*)d_in[2];
  const float* bs = (const float*)d_in[3];
  float* out = (float*)d_out;

  const size_t xqBytes = (size_t)TOKENS * IN_F;       // 32 MiB
  const size_t wqBytes = (size_t)OUT_F * IN_F;        // 43 MiB
  const size_t sxBytes = (size_t)TOKENS * sizeof(float);

  if (ws_size >= xqBytes + wqBytes + sxBytes) {
    signed char* xq = (signed char*)d_ws;
    signed char* wq = (signed char*)((char*)d_ws + xqBytes);
    float*       sx = (float*)((char*)d_ws + xqBytes + wqBytes);
    quant_x_kernel<<<TOKENS, 256, 0, stream>>>(x, xq, sx);
    cvt_w_kernel<<<2048, 256, 0, stream>>>(qw, wq, OUT_F * IN_F / 16);
    (void)hipFuncSetAttribute((const void*)gemm_i8_kernel,
                              hipFuncAttributeMaxDynamicSharedMemorySize,
                              LDS_TOTAL);
    gemm_i8_kernel<<<NWG, 512, LDS_TOTAL, stream>>>(xq, wq, sx, sc, bs, out);
  } else {
    long long total = (long long)TOKENS * OUT_F;
    int blocks = (int)((total + 255) / 256);
    gemm_naive_kernel<<<blocks, 256, 0, stream>>>(x, qw, sc, bs, out);
  }
}